// Round 7
// baseline (153.851 us; speedup 1.0000x reference)
//
#include <hip/hip_runtime.h>
#include <hip/hip_bf16.h>

// Problem constants (B=2, T=2048, C=1024, H=16, hd=64)
#define TT    2048
#define CC    1024
#define N3C   3072
#define MROWS 4096   // B*T

typedef __attribute__((ext_vector_type(8))) short short8;
typedef __attribute__((ext_vector_type(4))) float floatx4;

#define MAX3(a, b, c) fmaxf(fmaxf((a), (b)), (c))

static __device__ __forceinline__ unsigned short f2bf(float f) {
  union { float f; unsigned u; } v; v.f = f;
  return (unsigned short)((v.u + 0x7fffu + ((v.u >> 16) & 1u)) >> 16);
}
static __device__ __forceinline__ unsigned cvt_pk_bf16(float lo, float hi) {
  unsigned r;
  asm("v_cvt_pk_bf16_f32 %0, %1, %2" : "=v"(r) : "v"(lo), "v"(hi));
  return r;
}
static __device__ __forceinline__ float fast_exp2(float x) {
  float r;
  asm("v_exp_f32 %0, %1" : "=v"(r) : "v"(x));
  return r;
}

// ---------------- convert x f32 -> bf16 (xb lives in d_out scratch) ----------------
__global__ __launch_bounds__(256) void k_cvt_x(const float* __restrict__ x,
                                               unsigned short* __restrict__ xb) {
  int i = (blockIdx.x * 256 + threadIdx.x) * 8;
  float4 f0 = *reinterpret_cast<const float4*>(x + i);
  float4 f1 = *reinterpret_cast<const float4*>(x + i + 4);
  union { unsigned u[4]; short8 v; } pk;
  pk.u[0] = cvt_pk_bf16(f0.x, f0.y);
  pk.u[1] = cvt_pk_bf16(f0.z, f0.w);
  pk.u[2] = cvt_pk_bf16(f1.x, f1.y);
  pk.u[3] = cvt_pk_bf16(f1.z, f1.w);
  *reinterpret_cast<short8*>(xb + i) = pk.v;
}

// ---------------- transpose W1 [1024][3072] -> W1t bf16 [3072][1024] ----------------
__global__ __launch_bounds__(256) void k_tr_w1(const float* __restrict__ w,
                                               unsigned short* __restrict__ wt) {
  __shared__ float tile[32][33];
  int k0 = blockIdx.x * 32;   // over K=1024
  int n0 = blockIdx.y * 32;   // over N=3072
  int tx = threadIdx.x & 31;
  int ty = threadIdx.x >> 5;  // 0..7
#pragma unroll
  for (int j = 0; j < 4; ++j)
    tile[ty + 8 * j][tx] = w[(size_t)(k0 + ty + 8 * j) * N3C + n0 + tx];
  __syncthreads();
#pragma unroll
  for (int j = 0; j < 4; ++j)
    wt[(size_t)(n0 + ty + 8 * j) * CC + k0 + tx] = f2bf(tile[tx][ty + 8 * j]);
}

// ---------------- QKV GEMM: xb[4096,1024](bf16) x W1t + b1 -> qkv bf16 ----------------
// 128x128 tile, BK=64, 4 waves. Both operands staged via global_load_lds (16B).
// Q columns (col < CC) pre-scaled by 1/(sqrt(1024)*ln2): attention works in log2 domain.
__global__ __launch_bounds__(256) void k_qkv_gemm(const unsigned short* __restrict__ xb,
                                                  const unsigned short* __restrict__ wt,
                                                  const float* __restrict__ b1,
                                                  unsigned short* __restrict__ qkv) {
  __shared__ unsigned short lA[128 * 64];
  __shared__ unsigned short lB[128 * 64];
  const int tid = threadIdx.x;
  const int bm = blockIdx.x;       // 0..31
  const int bn = blockIdx.y;       // 0..23
  const int wid = tid >> 6, lane = tid & 63;
  const int wr = wid >> 1, wc = wid & 1;
  const int lr = lane & 15;
  const int lg = lane >> 4;
  const int lk = lg * 8;

  floatx4 acc[4][4] = {};

  for (int kt = 0; kt < CC; kt += 64) {
#pragma unroll
    for (int c = 0; c < 4; ++c) {
      int eo = c * 2048 + tid * 8;         // element offset in [128][64] tile
      int row = eo >> 6, col = eo & 63;
      const unsigned short* ga = xb + (size_t)(bm * 128 + row) * CC + kt + col;
      __builtin_amdgcn_global_load_lds((const __attribute__((address_space(1))) void*)ga,
                                       (__attribute__((address_space(3))) void*)(lA + eo), 16, 0, 0);
      const unsigned short* gb = wt + (size_t)(bn * 128 + row) * CC + kt + col;
      __builtin_amdgcn_global_load_lds((const __attribute__((address_space(1))) void*)gb,
                                       (__attribute__((address_space(3))) void*)(lB + eo), 16, 0, 0);
    }
    __syncthreads();
#pragma unroll
    for (int ks = 0; ks < 2; ++ks) {
      short8 a[4], b[4];
#pragma unroll
      for (int m = 0; m < 4; ++m)
        a[m] = *reinterpret_cast<const short8*>(lA + (wr * 64 + m * 16 + lr) * 64 + ks * 32 + lk);
#pragma unroll
      for (int n = 0; n < 4; ++n)
        b[n] = *reinterpret_cast<const short8*>(lB + (wc * 64 + n * 16 + lr) * 64 + ks * 32 + lk);
#pragma unroll
      for (int m = 0; m < 4; ++m)
#pragma unroll
        for (int n = 0; n < 4; ++n)
          acc[m][n] = __builtin_amdgcn_mfma_f32_16x16x32_bf16(a[m], b[n], acc[m][n], 0, 0, 0);
    }
    __syncthreads();
  }

  const int rowb = bm * 128 + wr * 64;
  const int colb = bn * 128 + wc * 64;
#pragma unroll
  for (int n = 0; n < 4; ++n) {
    int col = colb + n * 16 + lr;
    float bias = b1[col];
    // Q: fold 1/sqrt(d_model) AND 1/ln2 (log2-domain softmax) = 0.03125/ln2
    float scl = (col < CC) ? 0.045084372f : 1.0f;
#pragma unroll
    for (int m = 0; m < 4; ++m)
#pragma unroll
      for (int r = 0; r < 4; ++r) {
        int row = rowb + m * 16 + lg * 4 + r;
        qkv[(size_t)row * N3C + col] = f2bf((acc[m][n][r] + bias) * scl);
      }
  }
}

// ---------------- Flash attention: qkv bf16 -> sdp f32 [4096][1024] (in d_out) ----------------
// block = 64 q-rows of one (b,h); 2 waves x 32 q each (2 q-fragments per wave).
// K/V LDS fragment reads are shared across both q-fragments (halved per-query DS traffic).
// Swapped QK^T (S^T = K Q^T, log2 domain); per-lane softmax; in-register P transpose.
__global__ __launch_bounds__(128, 3) void k_attn(const unsigned short* __restrict__ qkv,
                                                 float* __restrict__ sdp) {
  __shared__ unsigned short lK[2][64 * 64];
  __shared__ unsigned short lVt[2][64 * 64];   // transposed: [hd][key], swizzled

  const int tid = threadIdx.x;        // 0..127
  const int lane = tid & 63, wid = tid >> 6;   // wid 0..1
  const int lr = lane & 15;
  const int lg = lane >> 4;           // 0..3
  const int lk = lg * 8;
  const int swm = (lr & 7) << 3;      // read-side swizzle mask

  const int bid = blockIdx.x;
  const int qb = bid & 31;
  const int h  = (bid >> 5) & 15;
  const int b  = bid >> 9;

  const int qrow0 = qb * 64 + wid * 32;   // wave covers 32 q-rows

  short8 aq[2][2];  // [qf][ks]
#pragma unroll
  for (int qf = 0; qf < 2; ++qf) {
    const size_t qbase = ((size_t)(b * TT + qrow0 + qf * 16 + lr)) * N3C + h * 64;
    aq[qf][0] = *reinterpret_cast<const short8*>(qkv + qbase + lk);
    aq[qf][1] = *reinterpret_cast<const short8*>(qkv + qbase + 32 + lk);
  }

  floatx4 o[2][4] = {};
  float mm[2] = {-1e30f, -1e30f}, ll[2] = {0.f, 0.f};

  // shfl source lanes for the P exchange (same lr, different lg group)
  const int srcA = ((2 * lg) & 3) * 16 + lr;
  const int srcB = ((2 * lg + 1) & 3) * 16 + lr;
  const int lg2 = lg >> 1;
  const int qown = lg * 4;                 // o-domain q base within 16 (rows qown..qown+3)
  const int statbase = (lane & 48) + qown; // lane holding stats for q=qown+r: statbase+r

  // K staging geometry (global source pre-swizzled, LDS dest linear); 4 chunks x 128 thr
  int keo[4], krow[4], kcol[4];
#pragma unroll
  for (int c = 0; c < 4; ++c) {
    keo[c] = c * 1024 + tid * 8;
    krow[c] = keo[c] >> 6;
    kcol[c] = (keo[c] & 63) ^ ((krow[c] & 7) << 3);
  }
  const size_t kbase = (size_t)(b * TT) * N3C + CC + h * 64;

  // V staging geometry: thread handles keys (2kp, 2kp+1) x 16 d-values (db*16..+15)
  const int kp = tid & 31;
  const int db = tid >> 5;  // 0..3
  const size_t vbase = ((size_t)(b * TT + 2 * kp)) * N3C + 2 * CC + h * 64 + db * 16;

  // ---- prologue: stage tile 0 ----
  {
#pragma unroll
    for (int c = 0; c < 4; ++c) {
      const unsigned short* g = qkv + kbase + (size_t)krow[c] * N3C + kcol[c];
      __builtin_amdgcn_global_load_lds((const __attribute__((address_space(1))) void*)g,
                                       (__attribute__((address_space(3))) void*)(&lK[0][0] + keo[c]), 16, 0, 0);
    }
    const unsigned short* gv = qkv + vbase;
    short8 v0a = *reinterpret_cast<const short8*>(gv);
    short8 v0b = *reinterpret_cast<const short8*>(gv + 8);
    short8 v1a = *reinterpret_cast<const short8*>(gv + N3C);
    short8 v1b = *reinterpret_cast<const short8*>(gv + N3C + 8);
#pragma unroll
    for (int j = 0; j < 8; ++j) {
      int rr = db * 16 + j;
      unsigned wrd = ((unsigned)(unsigned short)v0a[j]) | (((unsigned)(unsigned short)v1a[j]) << 16);
      *reinterpret_cast<unsigned*>(&lVt[0][rr * 64 + ((2 * kp) ^ ((j & 7) << 3))]) = wrd;
    }
#pragma unroll
    for (int j = 0; j < 8; ++j) {
      int rr = db * 16 + 8 + j;
      unsigned wrd = ((unsigned)(unsigned short)v0b[j]) | (((unsigned)(unsigned short)v1b[j]) << 16);
      *reinterpret_cast<unsigned*>(&lVt[0][rr * 64 + ((2 * kp) ^ ((j & 7) << 3))]) = wrd;
    }
  }
  __syncthreads();

  for (int kt = 0; kt < TT / 64; ++kt) {
    const int cur = kt & 1;
    short8 nv0a, nv0b, nv1a, nv1b;
    if (kt < TT / 64 - 1) {
      const size_t koff = kbase + (size_t)((kt + 1) * 64) * N3C;
#pragma unroll
      for (int c = 0; c < 4; ++c) {
        const unsigned short* g = qkv + koff + (size_t)krow[c] * N3C + kcol[c];
        __builtin_amdgcn_global_load_lds((const __attribute__((address_space(1))) void*)g,
                                         (__attribute__((address_space(3))) void*)(&lK[cur ^ 1][0] + keo[c]), 16, 0, 0);
      }
      const unsigned short* gv = qkv + vbase + (size_t)((kt + 1) * 64) * N3C;
      nv0a = *reinterpret_cast<const short8*>(gv);
      nv0b = *reinterpret_cast<const short8*>(gv + 8);
      nv1a = *reinterpret_cast<const short8*>(gv + N3C);
      nv1b = *reinterpret_cast<const short8*>(gv + N3C + 8);
    }

    // ---- S^T = K Q^T : lane holds S[key = n*16+lg*4+r][q = qf*16+lr] (log2 domain) ----
    // K-fragments read ONCE, reused for both q-fragments.
    floatx4 s[2][4];
    __builtin_amdgcn_s_setprio(1);
#pragma unroll
    for (int n = 0; n < 4; ++n) {
      short8 bk0 = *reinterpret_cast<const short8*>(
          &lK[cur][0] + (n * 16 + lr) * 64 + ((0 + lk) ^ swm));
      short8 bk1 = *reinterpret_cast<const short8*>(
          &lK[cur][0] + (n * 16 + lr) * 64 + ((32 + lk) ^ swm));
      floatx4 z0 = {}, z1 = {};
      z0 = __builtin_amdgcn_mfma_f32_16x16x32_bf16(bk0, aq[0][0], z0, 0, 0, 0);
      z0 = __builtin_amdgcn_mfma_f32_16x16x32_bf16(bk1, aq[0][1], z0, 0, 0, 0);
      z1 = __builtin_amdgcn_mfma_f32_16x16x32_bf16(bk0, aq[1][0], z1, 0, 0, 0);
      z1 = __builtin_amdgcn_mfma_f32_16x16x32_bf16(bk1, aq[1][1], z1, 0, 0, 0);
      s[0][n] = z0;
      s[1][n] = z1;
    }
    __builtin_amdgcn_s_setprio(0);

    // ---- per-qf softmax (base-2) + in-register P transpose ----
    short8 apc[2][2];  // [qf][ks] A-fragments for PV
#pragma unroll
    for (int qf = 0; qf < 2; ++qf) {
      float a0 = MAX3(s[qf][0][0], s[qf][0][1], s[qf][0][2]);
      float a1 = MAX3(s[qf][0][3], s[qf][1][0], s[qf][1][1]);
      float a2 = MAX3(s[qf][1][2], s[qf][1][3], s[qf][2][0]);
      float a3 = MAX3(s[qf][2][1], s[qf][2][2], s[qf][2][3]);
      float a4 = MAX3(s[qf][3][0], s[qf][3][1], s[qf][3][2]);
      float pmax = fmaxf(MAX3(a0, a1, a2), MAX3(a3, a4, s[qf][3][3]));
      pmax = fmaxf(pmax, __shfl_xor(pmax, 16));
      pmax = fmaxf(pmax, __shfl_xor(pmax, 32));

      if (__any(pmax > mm[qf] + 11.5f)) {      // defer-max (2^11.5 ~ e^8 headroom)
        float mnew = fmaxf(mm[qf], pmax);
        float alpha = fast_exp2(mm[qf] - mnew);
        mm[qf] = mnew;
        ll[qf] *= alpha;
        float c0 = __shfl(alpha, statbase + 0);
        float c1 = __shfl(alpha, statbase + 1);
        float c2 = __shfl(alpha, statbase + 2);
        float c3 = __shfl(alpha, statbase + 3);
#pragma unroll
        for (int n = 0; n < 4; ++n) {
          o[qf][n][0] *= c0; o[qf][n][1] *= c1; o[qf][n][2] *= c2; o[qf][n][3] *= c3;
        }
      }

      float p[4][4], lsum = 0.f;
#pragma unroll
      for (int n = 0; n < 4; ++n)
#pragma unroll
        for (int r = 0; r < 4; ++r) {
          p[n][r] = fast_exp2(s[qf][n][r] - mm[qf]);
          lsum += p[n][r];
        }
      lsum += __shfl_xor(lsum, 16);
      lsum += __shfl_xor(lsum, 32);
      ll[qf] += lsum;

      unsigned w[4][2];
#pragma unroll
      for (int n = 0; n < 4; ++n)
#pragma unroll
        for (int mi = 0; mi < 2; ++mi)
          w[n][mi] = cvt_pk_bf16(p[n][2 * mi], p[n][2 * mi + 1]);

      unsigned fw[2][4];
#pragma unroll
      for (int ks2 = 0; ks2 < 2; ++ks2)
#pragma unroll
        for (int M = 0; M < 2; ++M) {
          int g0A = __shfl((int)w[2 * ks2][M], srcA);
          int g0B = __shfl((int)w[2 * ks2][M], srcB);
          int g1A = __shfl((int)w[2 * ks2 + 1][M], srcA);
          int g1B = __shfl((int)w[2 * ks2 + 1][M], srcB);
          fw[ks2][M]     = (unsigned)(lg2 ? g1A : g0A);
          fw[ks2][M + 2] = (unsigned)(lg2 ? g1B : g0B);
        }
      union { unsigned u[4]; short8 v; } c0, c1;
#pragma unroll
      for (int j = 0; j < 4; ++j) { c0.u[j] = fw[0][j]; c1.u[j] = fw[1][j]; }
      apc[qf][0] = c0.v;
      apc[qf][1] = c1.v;
    }

    // ---- PV: o[qf][q=qf*16+lg*4+r][d=n*16+lr]; V-fragments read once, used 2x ----
    __builtin_amdgcn_s_setprio(1);
#pragma unroll
    for (int n = 0; n < 4; ++n) {
      short8 bv0 = *reinterpret_cast<const short8*>(
          &lVt[cur][0] + (n * 16 + lr) * 64 + ((0 + lk) ^ swm));
      short8 bv1 = *reinterpret_cast<const short8*>(
          &lVt[cur][0] + (n * 16 + lr) * 64 + ((32 + lk) ^ swm));
      o[0][n] = __builtin_amdgcn_mfma_f32_16x16x32_bf16(apc[0][0], bv0, o[0][n], 0, 0, 0);
      o[0][n] = __builtin_amdgcn_mfma_f32_16x16x32_bf16(apc[0][1], bv1, o[0][n], 0, 0, 0);
      o[1][n] = __builtin_amdgcn_mfma_f32_16x16x32_bf16(apc[1][0], bv0, o[1][n], 0, 0, 0);
      o[1][n] = __builtin_amdgcn_mfma_f32_16x16x32_bf16(apc[1][1], bv1, o[1][n], 0, 0, 0);
    }
    __builtin_amdgcn_s_setprio(0);

    // ---- write next V tile (b32 key-pairs, conflict-free), then one barrier ----
    if (kt < TT / 64 - 1) {
#pragma unroll
      for (int j = 0; j < 8; ++j) {
        int rr = db * 16 + j;
        unsigned wrd = ((unsigned)(unsigned short)nv0a[j]) | (((unsigned)(unsigned short)nv1a[j]) << 16);
        *reinterpret_cast<unsigned*>(&lVt[cur ^ 1][rr * 64 + ((2 * kp) ^ ((j & 7) << 3))]) = wrd;
      }
#pragma unroll
      for (int j = 0; j < 8; ++j) {
        int rr = db * 16 + 8 + j;
        unsigned wrd = ((unsigned)(unsigned short)nv0b[j]) | (((unsigned)(unsigned short)nv1b[j]) << 16);
        *reinterpret_cast<unsigned*>(&lVt[cur ^ 1][rr * 64 + ((2 * kp) ^ ((j & 7) << 3))]) = wrd;
      }
    }
    __syncthreads();  // drains vmcnt (K stage) + makes V writes visible
  }

  // epilogue: broadcast 1/l to o-domain, write merged-head sdp (f32)
#pragma unroll
  for (int qf = 0; qf < 2; ++qf) {
    float linv = 1.0f / ll[qf];
    float li0 = __shfl(linv, statbase + 0);
    float li1 = __shfl(linv, statbase + 1);
    float li2 = __shfl(linv, statbase + 2);
    float li3 = __shfl(linv, statbase + 3);
    const int orow0 = b * TT + qrow0 + qf * 16 + qown;
#pragma unroll
    for (int n = 0; n < 4; ++n) {
      sdp[(size_t)(orow0 + 0) * CC + h * 64 + n * 16 + lr] = o[qf][n][0] * li0;
      sdp[(size_t)(orow0 + 1) * CC + h * 64 + n * 16 + lr] = o[qf][n][1] * li1;
      sdp[(size_t)(orow0 + 2) * CC + h * 64 + n * 16 + lr] = o[qf][n][2] * li2;
      sdp[(size_t)(orow0 + 3) * CC + h * 64 + n * 16 + lr] = o[qf][n][3] * li3;
    }
  }
}

// ---------------- residual + LayerNorm, in-place on io (f32 sdp -> f32 out) ----------------
__global__ __launch_bounds__(256) void k_ln(const float* __restrict__ x,
                                            const float* __restrict__ gamma,
                                            const float* __restrict__ beta,
                                            float* io) {
  __shared__ float red[2][4];
  const int row = blockIdx.x;
  const int tid = threadIdx.x;
  const int i0 = tid * 4;
  float4 xv = *reinterpret_cast<const float4*>(x + (size_t)row * CC + i0);
  float4 sv = *reinterpret_cast<const float4*>(io + (size_t)row * CC + i0);
  float y[4] = {xv.x + sv.x, xv.y + sv.y, xv.z + sv.z, xv.w + sv.w};
  float s = y[0] + y[1] + y[2] + y[3];
  float s2 = y[0] * y[0] + y[1] * y[1] + y[2] * y[2] + y[3] * y[3];
#pragma unroll
  for (int msk = 1; msk < 64; msk <<= 1) {
    s += __shfl_xor(s, msk);
    s2 += __shfl_xor(s2, msk);
  }
  const int wid = tid >> 6;
  if ((tid & 63) == 0) { red[0][wid] = s; red[1][wid] = s2; }
  __syncthreads();
  s = red[0][0] + red[0][1] + red[0][2] + red[0][3];
  s2 = red[1][0] + red[1][1] + red[1][2] + red[1][3];
  float mean = s * (1.0f / CC);
  float var = s2 * (1.0f / CC) - mean * mean;
  float rstd = rsqrtf(var + 1e-6f);
  float4 r;
  r.x = (y[0] - mean) * rstd * gamma[i0 + 0] + beta[i0 + 0];
  r.y = (y[1] - mean) * rstd * gamma[i0 + 1] + beta[i0 + 1];
  r.z = (y[2] - mean) * rstd * gamma[i0 + 2] + beta[i0 + 2];
  r.w = (y[3] - mean) * rstd * gamma[i0 + 3] + beta[i0 + 3];
  *reinterpret_cast<float4*>(io + (size_t)row * CC + i0) = r;
}

extern "C" void kernel_launch(void* const* d_in, const int* in_sizes, int n_in,
                              void* d_out, int out_size, void* d_ws, size_t ws_size,
                              hipStream_t stream) {
  const float* x     = (const float*)d_in[0];
  const float* W1    = (const float*)d_in[1];
  const float* b1    = (const float*)d_in[2];
  const float* gamma = (const float*)d_in[3];
  const float* beta  = (const float*)d_in[4];

  // Memory plan: qkv bf16 (25.2 MB) is the ONLY d_ws user.
  // d_out (16.78 MB f32) doubles as scratch:
  //   [0, 6.29MB)      W1t bf16   (dead after GEMM)
  //   [6.29, 14.68MB)  xb bf16    (dead after GEMM)
  // then k_attn overwrites all of d_out with sdp f32; LN runs in-place.
  unsigned short* qkv = (unsigned short*)d_ws;
  unsigned short* w1t = (unsigned short*)d_out;
  unsigned short* xb  = (unsigned short*)((char*)d_out + 6291456);
  float*          sdp = (float*)d_out;

  k_cvt_x<<<MROWS * CC / (256 * 8), 256, 0, stream>>>(x, xb);
  k_tr_w1<<<dim3(CC / 32, N3C / 32), 256, 0, stream>>>(W1, w1t);
  k_qkv_gemm<<<dim3(MROWS / 128, N3C / 128), 256, 0, stream>>>(xb, w1t, b1, qkv);
  k_attn<<<2 * 16 * (TT / 64), 128, 0, stream>>>(qkv, sdp);
  k_ln<<<MROWS, 256, 0, stream>>>(x, gamma, beta, sdp);
}

// Round 8
// 136.515 us; speedup vs baseline: 1.1270x; 1.1270x over previous
//
#include <hip/hip_runtime.h>
#include <hip/hip_bf16.h>

// Problem constants (B=2, T=2048, C=1024, H=16, hd=64)
#define TT    2048
#define CC    1024
#define N3C   3072
#define MROWS 4096   // B*T

typedef __attribute__((ext_vector_type(8))) short short8;
typedef __attribute__((ext_vector_type(4))) float floatx4;

#define MAX3(a, b, c) fmaxf(fmaxf((a), (b)), (c))

static __device__ __forceinline__ unsigned short f2bf(float f) {
  union { float f; unsigned u; } v; v.f = f;
  return (unsigned short)((v.u + 0x7fffu + ((v.u >> 16) & 1u)) >> 16);
}
static __device__ __forceinline__ unsigned cvt_pk_bf16(float lo, float hi) {
  unsigned r;
  asm("v_cvt_pk_bf16_f32 %0, %1, %2" : "=v"(r) : "v"(lo), "v"(hi));
  return r;
}
static __device__ __forceinline__ float fast_exp2(float x) {
  float r;
  asm("v_exp_f32 %0, %1" : "=v"(r) : "v"(x));
  return r;
}

// ---------------- convert x f32 -> bf16 (xb lives in d_out scratch) ----------------
__global__ __launch_bounds__(256) void k_cvt_x(const float* __restrict__ x,
                                               unsigned short* __restrict__ xb) {
  int i = (blockIdx.x * 256 + threadIdx.x) * 8;
  float4 f0 = *reinterpret_cast<const float4*>(x + i);
  float4 f1 = *reinterpret_cast<const float4*>(x + i + 4);
  union { unsigned u[4]; short8 v; } pk;
  pk.u[0] = cvt_pk_bf16(f0.x, f0.y);
  pk.u[1] = cvt_pk_bf16(f0.z, f0.w);
  pk.u[2] = cvt_pk_bf16(f1.x, f1.y);
  pk.u[3] = cvt_pk_bf16(f1.z, f1.w);
  *reinterpret_cast<short8*>(xb + i) = pk.v;
}

// ---------------- transpose W1 [1024][3072] -> W1t bf16 [3072][1024] ----------------
__global__ __launch_bounds__(256) void k_tr_w1(const float* __restrict__ w,
                                               unsigned short* __restrict__ wt) {
  __shared__ float tile[32][33];
  int k0 = blockIdx.x * 32;   // over K=1024
  int n0 = blockIdx.y * 32;   // over N=3072
  int tx = threadIdx.x & 31;
  int ty = threadIdx.x >> 5;  // 0..7
#pragma unroll
  for (int j = 0; j < 4; ++j)
    tile[ty + 8 * j][tx] = w[(size_t)(k0 + ty + 8 * j) * N3C + n0 + tx];
  __syncthreads();
#pragma unroll
  for (int j = 0; j < 4; ++j)
    wt[(size_t)(n0 + ty + 8 * j) * CC + k0 + tx] = f2bf(tile[tx][ty + 8 * j]);
}

// ---------------- QKV GEMM: xb[4096,1024](bf16) x W1t + b1 -> qkv bf16 ----------------
// 128x128 tile, BK=64, 4 waves. Both operands staged via global_load_lds (16B).
// Q columns (col < CC) pre-scaled by 1/(sqrt(1024)*ln2): attention works in log2 domain.
__global__ __launch_bounds__(256) void k_qkv_gemm(const unsigned short* __restrict__ xb,
                                                  const unsigned short* __restrict__ wt,
                                                  const float* __restrict__ b1,
                                                  unsigned short* __restrict__ qkv) {
  __shared__ unsigned short lA[128 * 64];
  __shared__ unsigned short lB[128 * 64];
  const int tid = threadIdx.x;
  const int bm = blockIdx.x;       // 0..31
  const int bn = blockIdx.y;       // 0..23
  const int wid = tid >> 6, lane = tid & 63;
  const int wr = wid >> 1, wc = wid & 1;
  const int lr = lane & 15;
  const int lg = lane >> 4;
  const int lk = lg * 8;

  floatx4 acc[4][4] = {};

  for (int kt = 0; kt < CC; kt += 64) {
#pragma unroll
    for (int c = 0; c < 4; ++c) {
      int eo = c * 2048 + tid * 8;         // element offset in [128][64] tile
      int row = eo >> 6, col = eo & 63;
      const unsigned short* ga = xb + (size_t)(bm * 128 + row) * CC + kt + col;
      __builtin_amdgcn_global_load_lds((const __attribute__((address_space(1))) void*)ga,
                                       (__attribute__((address_space(3))) void*)(lA + eo), 16, 0, 0);
      const unsigned short* gb = wt + (size_t)(bn * 128 + row) * CC + kt + col;
      __builtin_amdgcn_global_load_lds((const __attribute__((address_space(1))) void*)gb,
                                       (__attribute__((address_space(3))) void*)(lB + eo), 16, 0, 0);
    }
    __syncthreads();
#pragma unroll
    for (int ks = 0; ks < 2; ++ks) {
      short8 a[4], b[4];
#pragma unroll
      for (int m = 0; m < 4; ++m)
        a[m] = *reinterpret_cast<const short8*>(lA + (wr * 64 + m * 16 + lr) * 64 + ks * 32 + lk);
#pragma unroll
      for (int n = 0; n < 4; ++n)
        b[n] = *reinterpret_cast<const short8*>(lB + (wc * 64 + n * 16 + lr) * 64 + ks * 32 + lk);
#pragma unroll
      for (int m = 0; m < 4; ++m)
#pragma unroll
        for (int n = 0; n < 4; ++n)
          acc[m][n] = __builtin_amdgcn_mfma_f32_16x16x32_bf16(a[m], b[n], acc[m][n], 0, 0, 0);
    }
    __syncthreads();
  }

  const int rowb = bm * 128 + wr * 64;
  const int colb = bn * 128 + wc * 64;
#pragma unroll
  for (int n = 0; n < 4; ++n) {
    int col = colb + n * 16 + lr;
    float bias = b1[col];
    // Q: fold 1/sqrt(d_model) AND 1/ln2 (log2-domain softmax) = 0.03125/ln2
    float scl = (col < CC) ? 0.045084372f : 1.0f;
#pragma unroll
    for (int m = 0; m < 4; ++m)
#pragma unroll
      for (int r = 0; r < 4; ++r) {
        int row = rowb + m * 16 + lg * 4 + r;
        qkv[(size_t)row * N3C + col] = f2bf((acc[m][n][r] + bias) * scl);
      }
  }
}

// ---------------- Flash attention: qkv bf16 -> sdp f32 [4096][1024] (in d_out) ----------------
// block = 64 q-rows of one (b,h); 4 waves x 16 q; KV tiles of 64.
// Swapped QK^T (S^T = K Q^T, log2 domain); per-lane softmax.
// V staged with sigma-permuted key columns (bit shuffle [n1n0 g1g0 r1r0]->[n0 g1g0 n1 r1r0])
// so the P -> PV-A-fragment relayout is PURE IN-LANE (8 cvt_pk, ZERO shuffles).
__global__ __launch_bounds__(256) void k_attn(const unsigned short* __restrict__ qkv,
                                              float* __restrict__ sdp) {
  __shared__ unsigned short lK[2][64 * 64];
  __shared__ unsigned short lVt[2][64 * 64];   // transposed: [hd][sigma(key)], swizzled

  const int tid = threadIdx.x;
  const int lane = tid & 63, wid = tid >> 6;
  const int lr = lane & 15;
  const int lg = lane >> 4;          // 0..3
  const int lk = lg * 8;
  const int swm = (lr & 7) << 3;     // read-side swizzle mask

  const int bid = blockIdx.x;
  const int qb = bid & 31;
  const int h  = (bid >> 5) & 15;
  const int b  = bid >> 9;

  const int qrow0 = qb * 64 + wid * 16;
  const size_t qbase = ((size_t)(b * TT + qrow0 + lr)) * N3C + h * 64;

  short8 aq[2];
  aq[0] = *reinterpret_cast<const short8*>(qkv + qbase + lk);
  aq[1] = *reinterpret_cast<const short8*>(qkv + qbase + 32 + lk);

  floatx4 o[4] = {};
  float m = -1e30f, l = 0.f;   // stats for query q = lr (log2 domain)

  const int qown = lg * 4;                 // o-domain q base (rows qown..qown+3)
  const int statbase = (lane & 48) + qown; // lane holding stats for q=qown+r: statbase+r

  // K staging geometry (global source pre-swizzled, LDS dest linear)
  const int keo0 = tid * 8;
  const int krow0 = keo0 >> 6, kcol0 = (keo0 & 63) ^ ((krow0 & 7) << 3);
  const int keo1 = 2048 + tid * 8;
  const int krow1 = keo1 >> 6, kcol1 = (keo1 & 63) ^ ((krow1 & 7) << 3);
  const size_t kbase = (size_t)(b * TT) * N3C + CC + h * 64;

  // V staging: thread handles global keys (2kp, 2kp+1) x 8 d-values (db*8..+7),
  // written to lVt columns (vsig, vsig+1) where vsig = sigma(2kp).
  const int kp = tid & 31;
  const int db = tid >> 5;
  const int vsig = 32 * ((kp >> 3) & 1) + 8 * ((kp >> 1) & 3) + 4 * (kp >> 4) + 2 * (kp & 1);
  const size_t vbase = ((size_t)(b * TT + 2 * kp)) * N3C + 2 * CC + h * 64 + db * 8;

  // ---- prologue: stage tile 0 ----
  {
    const unsigned short* g0 = qkv + kbase + (size_t)krow0 * N3C + kcol0;
    __builtin_amdgcn_global_load_lds((const __attribute__((address_space(1))) void*)g0,
                                     (__attribute__((address_space(3))) void*)(&lK[0][0] + keo0), 16, 0, 0);
    const unsigned short* g1 = qkv + kbase + (size_t)krow1 * N3C + kcol1;
    __builtin_amdgcn_global_load_lds((const __attribute__((address_space(1))) void*)g1,
                                     (__attribute__((address_space(3))) void*)(&lK[0][0] + keo1), 16, 0, 0);
    short8 v0 = *reinterpret_cast<const short8*>(qkv + vbase);
    short8 v1 = *reinterpret_cast<const short8*>(qkv + vbase + N3C);
#pragma unroll
    for (int j = 0; j < 8; ++j) {
      int rr = db * 8 + j;
      int col0 = vsig ^ (j << 3);
      unsigned wrd = ((unsigned)(unsigned short)v0[j]) | (((unsigned)(unsigned short)v1[j]) << 16);
      *reinterpret_cast<unsigned*>(&lVt[0][rr * 64 + col0]) = wrd;
    }
  }
  __syncthreads();

  for (int kt = 0; kt < TT / 64; ++kt) {
    const int cur = kt & 1;
    short8 nv0, nv1;
    if (kt < TT / 64 - 1) {
      const size_t koff = kbase + (size_t)((kt + 1) * 64) * N3C;
      const unsigned short* g0 = qkv + koff + (size_t)krow0 * N3C + kcol0;
      __builtin_amdgcn_global_load_lds((const __attribute__((address_space(1))) void*)g0,
                                       (__attribute__((address_space(3))) void*)(&lK[cur ^ 1][0] + keo0), 16, 0, 0);
      const unsigned short* g1 = qkv + koff + (size_t)krow1 * N3C + kcol1;
      __builtin_amdgcn_global_load_lds((const __attribute__((address_space(1))) void*)g1,
                                       (__attribute__((address_space(3))) void*)(&lK[cur ^ 1][0] + keo1), 16, 0, 0);
      const unsigned short* gv = qkv + vbase + (size_t)((kt + 1) * 64) * N3C;
      nv0 = *reinterpret_cast<const short8*>(gv);
      nv1 = *reinterpret_cast<const short8*>(gv + N3C);
    }

    // ---- S^T = K Q^T : lane holds S[key = 16n + 4lg + r][q = lr] (log2 domain) ----
    floatx4 s[4];
    __builtin_amdgcn_s_setprio(1);
#pragma unroll
    for (int n = 0; n < 4; ++n) {
      floatx4 z = {};
#pragma unroll
      for (int ks = 0; ks < 2; ++ks) {
        short8 bk = *reinterpret_cast<const short8*>(
            &lK[cur][0] + (n * 16 + lr) * 64 + ((ks * 32 + lk) ^ swm));
        z = __builtin_amdgcn_mfma_f32_16x16x32_bf16(bk, aq[ks], z, 0, 0, 0);
      }
      s[n] = z;
    }
    __builtin_amdgcn_s_setprio(0);

    // ---- per-lane online softmax (base-2) over this tile's 64 keys for q=lr ----
    float a0 = MAX3(s[0][0], s[0][1], s[0][2]);
    float a1 = MAX3(s[0][3], s[1][0], s[1][1]);
    float a2 = MAX3(s[1][2], s[1][3], s[2][0]);
    float a3 = MAX3(s[2][1], s[2][2], s[2][3]);
    float a4 = MAX3(s[3][0], s[3][1], s[3][2]);
    float pmax = fmaxf(MAX3(a0, a1, a2), MAX3(a3, a4, s[3][3]));
    pmax = fmaxf(pmax, __shfl_xor(pmax, 16));
    pmax = fmaxf(pmax, __shfl_xor(pmax, 32));

    if (__any(pmax > m + 11.5f)) {        // defer-max (2^11.5 ~ e^8 headroom)
      float mnew = fmaxf(m, pmax);
      float alpha = fast_exp2(m - mnew);
      m = mnew;
      l *= alpha;
      float b0 = __shfl(alpha, statbase + 0);
      float b1_ = __shfl(alpha, statbase + 1);
      float b2 = __shfl(alpha, statbase + 2);
      float b3 = __shfl(alpha, statbase + 3);
#pragma unroll
      for (int n = 0; n < 4; ++n) {
        o[n][0] *= b0; o[n][1] *= b1_; o[n][2] *= b2; o[n][3] *= b3;
      }
    }

    float p[4][4], lsum = 0.f;
#pragma unroll
    for (int n = 0; n < 4; ++n)
#pragma unroll
      for (int r = 0; r < 4; ++r) {
        p[n][r] = fast_exp2(s[n][r] - m);
        lsum += p[n][r];
      }
    lsum += __shfl_xor(lsum, 16);
    lsum += __shfl_xor(lsum, 32);
    l += lsum;

    // ---- P -> A-fragments, PURE IN-LANE (sigma-permuted V makes this legal) ----
    // apc[ks].word[w] packs p[2*(w>>1)+ks][2*(w&1)], p[...][2*(w&1)+1]
    union { unsigned u[4]; short8 v; } c0, c1;
#pragma unroll
    for (int w = 0; w < 4; ++w) {
      int nb = 2 * (w >> 1);
      int rb = 2 * (w & 1);
      c0.u[w] = cvt_pk_bf16(p[nb + 0][rb], p[nb + 0][rb + 1]);
      c1.u[w] = cvt_pk_bf16(p[nb + 1][rb], p[nb + 1][rb + 1]);
    }

    // ---- PV: o[q=4lg+r][d=n*16+lr] += A x V(sigma) ----
    __builtin_amdgcn_s_setprio(1);
#pragma unroll
    for (int n = 0; n < 4; ++n) {
      short8 bv0 = *reinterpret_cast<const short8*>(
          &lVt[cur][0] + (n * 16 + lr) * 64 + ((0 + lk) ^ swm));
      o[n] = __builtin_amdgcn_mfma_f32_16x16x32_bf16(c0.v, bv0, o[n], 0, 0, 0);
      short8 bv1 = *reinterpret_cast<const short8*>(
          &lVt[cur][0] + (n * 16 + lr) * 64 + ((32 + lk) ^ swm));
      o[n] = __builtin_amdgcn_mfma_f32_16x16x32_bf16(c1.v, bv1, o[n], 0, 0, 0);
    }
    __builtin_amdgcn_s_setprio(0);

    // ---- write next V tile (b32 key-pairs at sigma columns), then one barrier ----
    if (kt < TT / 64 - 1) {
#pragma unroll
      for (int j = 0; j < 8; ++j) {
        int rr = db * 8 + j;
        int col0 = vsig ^ (j << 3);
        unsigned wrd = ((unsigned)(unsigned short)nv0[j]) | (((unsigned)(unsigned short)nv1[j]) << 16);
        *reinterpret_cast<unsigned*>(&lVt[cur ^ 1][rr * 64 + col0]) = wrd;
      }
    }
    __syncthreads();  // drains vmcnt (K stage) + makes V writes visible
  }

  // epilogue: broadcast 1/l to o-domain, write merged-head sdp (f32)
  float linv = 1.0f / l;
  float li0 = __shfl(linv, statbase + 0);
  float li1 = __shfl(linv, statbase + 1);
  float li2 = __shfl(linv, statbase + 2);
  float li3 = __shfl(linv, statbase + 3);
  const int orow0 = b * TT + qrow0 + qown;
#pragma unroll
  for (int n = 0; n < 4; ++n) {
    sdp[(size_t)(orow0 + 0) * CC + h * 64 + n * 16 + lr] = o[n][0] * li0;
    sdp[(size_t)(orow0 + 1) * CC + h * 64 + n * 16 + lr] = o[n][1] * li1;
    sdp[(size_t)(orow0 + 2) * CC + h * 64 + n * 16 + lr] = o[n][2] * li2;
    sdp[(size_t)(orow0 + 3) * CC + h * 64 + n * 16 + lr] = o[n][3] * li3;
  }
}

// ---------------- residual + LayerNorm, in-place on io (f32 sdp -> f32 out) ----------------
__global__ __launch_bounds__(256) void k_ln(const float* __restrict__ x,
                                            const float* __restrict__ gamma,
                                            const float* __restrict__ beta,
                                            float* io) {
  __shared__ float red[2][4];
  const int row = blockIdx.x;
  const int tid = threadIdx.x;
  const int i0 = tid * 4;
  float4 xv = *reinterpret_cast<const float4*>(x + (size_t)row * CC + i0);
  float4 sv = *reinterpret_cast<const float4*>(io + (size_t)row * CC + i0);
  float y[4] = {xv.x + sv.x, xv.y + sv.y, xv.z + sv.z, xv.w + sv.w};
  float s = y[0] + y[1] + y[2] + y[3];
  float s2 = y[0] * y[0] + y[1] * y[1] + y[2] * y[2] + y[3] * y[3];
#pragma unroll
  for (int msk = 1; msk < 64; msk <<= 1) {
    s += __shfl_xor(s, msk);
    s2 += __shfl_xor(s2, msk);
  }
  const int wid = tid >> 6;
  if ((tid & 63) == 0) { red[0][wid] = s; red[1][wid] = s2; }
  __syncthreads();
  s = red[0][0] + red[0][1] + red[0][2] + red[0][3];
  s2 = red[1][0] + red[1][1] + red[1][2] + red[1][3];
  float mean = s * (1.0f / CC);
  float var = s2 * (1.0f / CC) - mean * mean;
  float rstd = rsqrtf(var + 1e-6f);
  float4 r;
  r.x = (y[0] - mean) * rstd * gamma[i0 + 0] + beta[i0 + 0];
  r.y = (y[1] - mean) * rstd * gamma[i0 + 1] + beta[i0 + 1];
  r.z = (y[2] - mean) * rstd * gamma[i0 + 2] + beta[i0 + 2];
  r.w = (y[3] - mean) * rstd * gamma[i0 + 3] + beta[i0 + 3];
  *reinterpret_cast<float4*>(io + (size_t)row * CC + i0) = r;
}

extern "C" void kernel_launch(void* const* d_in, const int* in_sizes, int n_in,
                              void* d_out, int out_size, void* d_ws, size_t ws_size,
                              hipStream_t stream) {
  const float* x     = (const float*)d_in[0];
  const float* W1    = (const float*)d_in[1];
  const float* b1    = (const float*)d_in[2];
  const float* gamma = (const float*)d_in[3];
  const float* beta  = (const float*)d_in[4];

  // Memory plan: qkv bf16 (25.2 MB) is the ONLY d_ws user.
  // d_out (16.78 MB f32) doubles as scratch:
  //   [0, 6.29MB)      W1t bf16   (dead after GEMM)
  //   [6.29, 14.68MB)  xb bf16    (dead after GEMM)
  // then k_attn overwrites all of d_out with sdp f32; LN runs in-place.
  unsigned short* qkv = (unsigned short*)d_ws;
  unsigned short* w1t = (unsigned short*)d_out;
  unsigned short* xb  = (unsigned short*)((char*)d_out + 6291456);
  float*          sdp = (float*)d_out;

  k_cvt_x<<<MROWS * CC / (256 * 8), 256, 0, stream>>>(x, xb);
  k_tr_w1<<<dim3(CC / 32, N3C / 32), 256, 0, stream>>>(W1, w1t);
  k_qkv_gemm<<<dim3(MROWS / 128, N3C / 128), 256, 0, stream>>>(xb, w1t, b1, qkv);
  k_attn<<<2 * 16 * (TT / 64), 256, 0, stream>>>(qkv, sdp);
  k_ln<<<MROWS, 256, 0, stream>>>(x, gamma, beta, sdp);
}

// Round 9
// 132.577 us; speedup vs baseline: 1.1605x; 1.0297x over previous
//
#include <hip/hip_runtime.h>
#include <hip/hip_bf16.h>

// Problem constants (B=2, T=2048, C=1024, H=16, hd=64)
#define TT    2048
#define CC    1024
#define N3C   3072
#define MROWS 4096   // B*T

typedef __attribute__((ext_vector_type(8))) short short8;
typedef __attribute__((ext_vector_type(4))) float floatx4;

#define MAX3(a, b, c) fmaxf(fmaxf((a), (b)), (c))

static __device__ __forceinline__ unsigned short f2bf(float f) {
  union { float f; unsigned u; } v; v.f = f;
  return (unsigned short)((v.u + 0x7fffu + ((v.u >> 16) & 1u)) >> 16);
}
static __device__ __forceinline__ unsigned cvt_pk_bf16(float lo, float hi) {
  unsigned r;
  asm("v_cvt_pk_bf16_f32 %0, %1, %2" : "=v"(r) : "v"(lo), "v"(hi));
  return r;
}
static __device__ __forceinline__ float fast_exp2(float x) {
  float r;
  asm("v_exp_f32 %0, %1" : "=v"(r) : "v"(x));
  return r;
}

// ---------------- convert x f32 -> bf16 (xb lives in d_out scratch) ----------------
__global__ __launch_bounds__(256) void k_cvt_x(const float* __restrict__ x,
                                               unsigned short* __restrict__ xb) {
  int i = (blockIdx.x * 256 + threadIdx.x) * 8;
  float4 f0 = *reinterpret_cast<const float4*>(x + i);
  float4 f1 = *reinterpret_cast<const float4*>(x + i + 4);
  union { unsigned u[4]; short8 v; } pk;
  pk.u[0] = cvt_pk_bf16(f0.x, f0.y);
  pk.u[1] = cvt_pk_bf16(f0.z, f0.w);
  pk.u[2] = cvt_pk_bf16(f1.x, f1.y);
  pk.u[3] = cvt_pk_bf16(f1.z, f1.w);
  *reinterpret_cast<short8*>(xb + i) = pk.v;
}

// ---------------- transpose W1 [1024][3072] -> W1t bf16 [3072][1024] ----------------
__global__ __launch_bounds__(256) void k_tr_w1(const float* __restrict__ w,
                                               unsigned short* __restrict__ wt) {
  __shared__ float tile[32][33];
  int k0 = blockIdx.x * 32;   // over K=1024
  int n0 = blockIdx.y * 32;   // over N=3072
  int tx = threadIdx.x & 31;
  int ty = threadIdx.x >> 5;  // 0..7
#pragma unroll
  for (int j = 0; j < 4; ++j)
    tile[ty + 8 * j][tx] = w[(size_t)(k0 + ty + 8 * j) * N3C + n0 + tx];
  __syncthreads();
#pragma unroll
  for (int j = 0; j < 4; ++j)
    wt[(size_t)(n0 + ty + 8 * j) * CC + k0 + tx] = f2bf(tile[tx][ty + 8 * j]);
}

// ---------------- QKV GEMM: xb[4096,1024](bf16) x W1t + b1 -> qkv bf16 ----------------
// 128x128 tile, BK=64, 4 waves. Both operands staged via global_load_lds (16B).
// Q columns (col < CC) pre-scaled by 1/(sqrt(1024)*ln2): attention works in log2 domain.
__global__ __launch_bounds__(256) void k_qkv_gemm(const unsigned short* __restrict__ xb,
                                                  const unsigned short* __restrict__ wt,
                                                  const float* __restrict__ b1,
                                                  unsigned short* __restrict__ qkv) {
  __shared__ unsigned short lA[128 * 64];
  __shared__ unsigned short lB[128 * 64];
  const int tid = threadIdx.x;
  const int bm = blockIdx.x;       // 0..31
  const int bn = blockIdx.y;       // 0..23
  const int wid = tid >> 6, lane = tid & 63;
  const int wr = wid >> 1, wc = wid & 1;
  const int lr = lane & 15;
  const int lg = lane >> 4;
  const int lk = lg * 8;

  floatx4 acc[4][4] = {};

  for (int kt = 0; kt < CC; kt += 64) {
#pragma unroll
    for (int c = 0; c < 4; ++c) {
      int eo = c * 2048 + tid * 8;         // element offset in [128][64] tile
      int row = eo >> 6, col = eo & 63;
      const unsigned short* ga = xb + (size_t)(bm * 128 + row) * CC + kt + col;
      __builtin_amdgcn_global_load_lds((const __attribute__((address_space(1))) void*)ga,
                                       (__attribute__((address_space(3))) void*)(lA + eo), 16, 0, 0);
      const unsigned short* gb = wt + (size_t)(bn * 128 + row) * CC + kt + col;
      __builtin_amdgcn_global_load_lds((const __attribute__((address_space(1))) void*)gb,
                                       (__attribute__((address_space(3))) void*)(lB + eo), 16, 0, 0);
    }
    __syncthreads();
#pragma unroll
    for (int ks = 0; ks < 2; ++ks) {
      short8 a[4], b[4];
#pragma unroll
      for (int m = 0; m < 4; ++m)
        a[m] = *reinterpret_cast<const short8*>(lA + (wr * 64 + m * 16 + lr) * 64 + ks * 32 + lk);
#pragma unroll
      for (int n = 0; n < 4; ++n)
        b[n] = *reinterpret_cast<const short8*>(lB + (wc * 64 + n * 16 + lr) * 64 + ks * 32 + lk);
#pragma unroll
      for (int m = 0; m < 4; ++m)
#pragma unroll
        for (int n = 0; n < 4; ++n)
          acc[m][n] = __builtin_amdgcn_mfma_f32_16x16x32_bf16(a[m], b[n], acc[m][n], 0, 0, 0);
    }
    __syncthreads();
  }

  const int rowb = bm * 128 + wr * 64;
  const int colb = bn * 128 + wc * 64;
#pragma unroll
  for (int n = 0; n < 4; ++n) {
    int col = colb + n * 16 + lr;
    float bias = b1[col];
    // Q: fold 1/sqrt(d_model) AND 1/ln2 (log2-domain softmax) = 0.03125/ln2
    float scl = (col < CC) ? 0.045084372f : 1.0f;
#pragma unroll
    for (int m = 0; m < 4; ++m)
#pragma unroll
      for (int r = 0; r < 4; ++r) {
        int row = rowb + m * 16 + lg * 4 + r;
        qkv[(size_t)row * N3C + col] = f2bf((acc[m][n][r] + bias) * scl);
      }
  }
}

// ---------------- Flash attention: qkv bf16 -> sdp f32 [4096][1024] (in d_out) ----------------
// block = 64 q-rows of one (b,h); 4 waves x 16 q; KV tiles of 64.
// Swapped QK^T (S^T = K Q^T, log2 domain); per-lane softmax with in-lane partial l
// (cross-lane reduce only at epilogue) and branch-gated pmax reduce.
// V staged with sigma-permuted key columns -> P->A relayout is pure in-lane.
// XCD-aware block remap: all 32 qb-blocks of one (b,h) land on one XCD (L2 locality).
__global__ __launch_bounds__(256) void k_attn(const unsigned short* __restrict__ qkv,
                                              float* __restrict__ sdp) {
  __shared__ unsigned short lK[2][64 * 64];
  __shared__ unsigned short lVt[2][64 * 64];   // transposed: [hd][sigma(key)], swizzled

  const int tid = threadIdx.x;
  const int lane = tid & 63, wid = tid >> 6;
  const int lr = lane & 15;
  const int lg = lane >> 4;          // 0..3
  const int lk = lg * 8;
  const int swm = (lr & 7) << 3;     // read-side swizzle mask

  // XCD-aware remap (bijective): hh = (bid%8) + 8*((bid/8)>>5), qb = (bid/8)&31.
  // All 32 qb-blocks of one head hh keep bid%8 constant -> same XCD L2 caches K/V.
  const int bid = blockIdx.x;
  const int jj  = bid >> 3;
  const int hh  = (bid & 7) + 8 * (jj >> 5);   // 0..31 = b*16+h
  const int qb  = jj & 31;
  const int h   = hh & 15;
  const int b   = hh >> 4;

  const int qrow0 = qb * 64 + wid * 16;
  const size_t qbase = ((size_t)(b * TT + qrow0 + lr)) * N3C + h * 64;

  short8 aq[2];
  aq[0] = *reinterpret_cast<const short8*>(qkv + qbase + lk);
  aq[1] = *reinterpret_cast<const short8*>(qkv + qbase + 32 + lk);

  floatx4 o[4] = {};
  float m = -1e30f;        // running max for q=lr (log2 domain, synced across lg-lanes)
  float l = 0.f;           // PER-LANE partial denominator (this lane's keys only)

  const int qown = lg * 4;                 // o-domain q base (rows qown..qown+3)
  const int statbase = (lane & 48) + qown; // lane holding stats for q=qown+r: statbase+r

  // K staging geometry (global source pre-swizzled, LDS dest linear)
  const int keo0 = tid * 8;
  const int krow0 = keo0 >> 6, kcol0 = (keo0 & 63) ^ ((krow0 & 7) << 3);
  const int keo1 = 2048 + tid * 8;
  const int krow1 = keo1 >> 6, kcol1 = (keo1 & 63) ^ ((krow1 & 7) << 3);
  const size_t kbase = (size_t)(b * TT) * N3C + CC + h * 64;

  // V staging: thread handles global keys (2kp, 2kp+1) x 8 d-values (db*8..+7),
  // written to lVt columns (vsig, vsig+1) where vsig = sigma(2kp).
  const int kp = tid & 31;
  const int db = tid >> 5;
  const int vsig = 32 * ((kp >> 3) & 1) + 8 * ((kp >> 1) & 3) + 4 * (kp >> 4) + 2 * (kp & 1);
  const size_t vbase = ((size_t)(b * TT + 2 * kp)) * N3C + 2 * CC + h * 64 + db * 8;

  // ---- prologue: stage tile 0 ----
  {
    const unsigned short* g0 = qkv + kbase + (size_t)krow0 * N3C + kcol0;
    __builtin_amdgcn_global_load_lds((const __attribute__((address_space(1))) void*)g0,
                                     (__attribute__((address_space(3))) void*)(&lK[0][0] + keo0), 16, 0, 0);
    const unsigned short* g1 = qkv + kbase + (size_t)krow1 * N3C + kcol1;
    __builtin_amdgcn_global_load_lds((const __attribute__((address_space(1))) void*)g1,
                                     (__attribute__((address_space(3))) void*)(&lK[0][0] + keo1), 16, 0, 0);
    short8 v0 = *reinterpret_cast<const short8*>(qkv + vbase);
    short8 v1 = *reinterpret_cast<const short8*>(qkv + vbase + N3C);
#pragma unroll
    for (int j = 0; j < 8; ++j) {
      int rr = db * 8 + j;
      int col0 = vsig ^ (j << 3);
      unsigned wrd = ((unsigned)(unsigned short)v0[j]) | (((unsigned)(unsigned short)v1[j]) << 16);
      *reinterpret_cast<unsigned*>(&lVt[0][rr * 64 + col0]) = wrd;
    }
  }
  __syncthreads();

  for (int kt = 0; kt < TT / 64; ++kt) {
    const int cur = kt & 1;
    short8 nv0, nv1;
    if (kt < TT / 64 - 1) {
      const size_t koff = kbase + (size_t)((kt + 1) * 64) * N3C;
      const unsigned short* g0 = qkv + koff + (size_t)krow0 * N3C + kcol0;
      __builtin_amdgcn_global_load_lds((const __attribute__((address_space(1))) void*)g0,
                                       (__attribute__((address_space(3))) void*)(&lK[cur ^ 1][0] + keo0), 16, 0, 0);
      const unsigned short* g1 = qkv + koff + (size_t)krow1 * N3C + kcol1;
      __builtin_amdgcn_global_load_lds((const __attribute__((address_space(1))) void*)g1,
                                       (__attribute__((address_space(3))) void*)(&lK[cur ^ 1][0] + keo1), 16, 0, 0);
      const unsigned short* gv = qkv + vbase + (size_t)((kt + 1) * 64) * N3C;
      nv0 = *reinterpret_cast<const short8*>(gv);
      nv1 = *reinterpret_cast<const short8*>(gv + N3C);
    }

    // ---- S^T = K Q^T : lane holds S[key = 16n + 4lg + r][q = lr] (log2 domain) ----
    floatx4 s[4];
    __builtin_amdgcn_s_setprio(1);
#pragma unroll
    for (int n = 0; n < 4; ++n) {
      floatx4 z = {};
#pragma unroll
      for (int ks = 0; ks < 2; ++ks) {
        short8 bk = *reinterpret_cast<const short8*>(
            &lK[cur][0] + (n * 16 + lr) * 64 + ((ks * 32 + lk) ^ swm));
        z = __builtin_amdgcn_mfma_f32_16x16x32_bf16(bk, aq[ks], z, 0, 0, 0);
      }
      s[n] = z;
    }
    __builtin_amdgcn_s_setprio(0);

    // ---- per-lane online softmax (base-2): in-lane max over this lane's 16 keys ----
    float a0 = MAX3(s[0][0], s[0][1], s[0][2]);
    float a1 = MAX3(s[0][3], s[1][0], s[1][1]);
    float a2 = MAX3(s[1][2], s[1][3], s[2][0]);
    float a3 = MAX3(s[2][1], s[2][2], s[2][3]);
    float a4 = MAX3(s[3][0], s[3][1], s[3][2]);
    float pmax = fmaxf(MAX3(a0, a1, a2), MAX3(a3, a4, s[3][3]));

    // Branch-gated: cross-lane reduce + rescale only if some lane exceeds headroom.
    if (__any(pmax > m + 11.5f)) {        // defer-max (2^11.5 ~ e^8 headroom)
      float pm = fmaxf(pmax, __shfl_xor(pmax, 16));
      pm = fmaxf(pm, __shfl_xor(pm, 32));
      float mnew = fmaxf(m, pm);
      float alpha = fast_exp2(m - mnew);  // same for all 4 lg-lanes of this q
      m = mnew;
      l *= alpha;                         // per-lane partial l rescales in-lane
      float b0 = __shfl(alpha, statbase + 0);
      float b1_ = __shfl(alpha, statbase + 1);
      float b2 = __shfl(alpha, statbase + 2);
      float b3 = __shfl(alpha, statbase + 3);
#pragma unroll
      for (int n = 0; n < 4; ++n) {
        o[n][0] *= b0; o[n][1] *= b1_; o[n][2] *= b2; o[n][3] *= b3;
      }
    }

    // exp + tree-sum (depth 4, no cross-lane reduce here)
    float p[4][4];
#pragma unroll
    for (int n = 0; n < 4; ++n)
#pragma unroll
      for (int r = 0; r < 4; ++r)
        p[n][r] = fast_exp2(s[n][r] - m);
    float t0 = (p[0][0] + p[0][1]) + (p[0][2] + p[0][3]);
    float t1 = (p[1][0] + p[1][1]) + (p[1][2] + p[1][3]);
    float t2 = (p[2][0] + p[2][1]) + (p[2][2] + p[2][3]);
    float t3 = (p[3][0] + p[3][1]) + (p[3][2] + p[3][3]);
    l += (t0 + t1) + (t2 + t3);

    // ---- P -> A-fragments, PURE IN-LANE (sigma-permuted V makes this legal) ----
    union { unsigned u[4]; short8 v; } c0, c1;
#pragma unroll
    for (int w = 0; w < 4; ++w) {
      int nb = 2 * (w >> 1);
      int rb = 2 * (w & 1);
      c0.u[w] = cvt_pk_bf16(p[nb + 0][rb], p[nb + 0][rb + 1]);
      c1.u[w] = cvt_pk_bf16(p[nb + 1][rb], p[nb + 1][rb + 1]);
    }

    // ---- PV: o[q=4lg+r][d=n*16+lr] += A x V(sigma) ----
    __builtin_amdgcn_s_setprio(1);
#pragma unroll
    for (int n = 0; n < 4; ++n) {
      short8 bv0 = *reinterpret_cast<const short8*>(
          &lVt[cur][0] + (n * 16 + lr) * 64 + ((0 + lk) ^ swm));
      o[n] = __builtin_amdgcn_mfma_f32_16x16x32_bf16(c0.v, bv0, o[n], 0, 0, 0);
      short8 bv1 = *reinterpret_cast<const short8*>(
          &lVt[cur][0] + (n * 16 + lr) * 64 + ((32 + lk) ^ swm));
      o[n] = __builtin_amdgcn_mfma_f32_16x16x32_bf16(c1.v, bv1, o[n], 0, 0, 0);
    }
    __builtin_amdgcn_s_setprio(0);

    // ---- write next V tile (b32 key-pairs at sigma columns), then one barrier ----
    if (kt < TT / 64 - 1) {
#pragma unroll
      for (int j = 0; j < 8; ++j) {
        int rr = db * 8 + j;
        int col0 = vsig ^ (j << 3);
        unsigned wrd = ((unsigned)(unsigned short)nv0[j]) | (((unsigned)(unsigned short)nv1[j]) << 16);
        *reinterpret_cast<unsigned*>(&lVt[cur ^ 1][rr * 64 + col0]) = wrd;
      }
    }
    __syncthreads();  // drains vmcnt (K stage) + makes V writes visible
  }

  // epilogue: reduce per-lane l across the 4 lg-lanes, broadcast 1/l, write sdp (f32)
  float lt = l + __shfl_xor(l, 16);
  lt += __shfl_xor(lt, 32);
  float linv = 1.0f / lt;
  float li0 = __shfl(linv, statbase + 0);
  float li1 = __shfl(linv, statbase + 1);
  float li2 = __shfl(linv, statbase + 2);
  float li3 = __shfl(linv, statbase + 3);
  const int orow0 = b * TT + qrow0 + qown;
#pragma unroll
  for (int n = 0; n < 4; ++n) {
    sdp[(size_t)(orow0 + 0) * CC + h * 64 + n * 16 + lr] = o[n][0] * li0;
    sdp[(size_t)(orow0 + 1) * CC + h * 64 + n * 16 + lr] = o[n][1] * li1;
    sdp[(size_t)(orow0 + 2) * CC + h * 64 + n * 16 + lr] = o[n][2] * li2;
    sdp[(size_t)(orow0 + 3) * CC + h * 64 + n * 16 + lr] = o[n][3] * li3;
  }
}

// ---------------- residual + LayerNorm, in-place on io (f32 sdp -> f32 out) ----------------
__global__ __launch_bounds__(256) void k_ln(const float* __restrict__ x,
                                            const float* __restrict__ gamma,
                                            const float* __restrict__ beta,
                                            float* io) {
  __shared__ float red[2][4];
  const int row = blockIdx.x;
  const int tid = threadIdx.x;
  const int i0 = tid * 4;
  float4 xv = *reinterpret_cast<const float4*>(x + (size_t)row * CC + i0);
  float4 sv = *reinterpret_cast<const float4*>(io + (size_t)row * CC + i0);
  float y[4] = {xv.x + sv.x, xv.y + sv.y, xv.z + sv.z, xv.w + sv.w};
  float s = y[0] + y[1] + y[2] + y[3];
  float s2 = y[0] * y[0] + y[1] * y[1] + y[2] * y[2] + y[3] * y[3];
#pragma unroll
  for (int msk = 1; msk < 64; msk <<= 1) {
    s += __shfl_xor(s, msk);
    s2 += __shfl_xor(s2, msk);
  }
  const int wid = tid >> 6;
  if ((tid & 63) == 0) { red[0][wid] = s; red[1][wid] = s2; }
  __syncthreads();
  s = red[0][0] + red[0][1] + red[0][2] + red[0][3];
  s2 = red[1][0] + red[1][1] + red[1][2] + red[1][3];
  float mean = s * (1.0f / CC);
  float var = s2 * (1.0f / CC) - mean * mean;
  float rstd = rsqrtf(var + 1e-6f);
  float4 r;
  r.x = (y[0] - mean) * rstd * gamma[i0 + 0] + beta[i0 + 0];
  r.y = (y[1] - mean) * rstd * gamma[i0 + 1] + beta[i0 + 1];
  r.z = (y[2] - mean) * rstd * gamma[i0 + 2] + beta[i0 + 2];
  r.w = (y[3] - mean) * rstd * gamma[i0 + 3] + beta[i0 + 3];
  *reinterpret_cast<float4*>(io + (size_t)row * CC + i0) = r;
}

extern "C" void kernel_launch(void* const* d_in, const int* in_sizes, int n_in,
                              void* d_out, int out_size, void* d_ws, size_t ws_size,
                              hipStream_t stream) {
  const float* x     = (const float*)d_in[0];
  const float* W1    = (const float*)d_in[1];
  const float* b1    = (const float*)d_in[2];
  const float* gamma = (const float*)d_in[3];
  const float* beta  = (const float*)d_in[4];

  // Memory plan: qkv bf16 (25.2 MB) is the ONLY d_ws user.
  // d_out (16.78 MB f32) doubles as scratch:
  //   [0, 6.29MB)      W1t bf16   (dead after GEMM)
  //   [6.29, 14.68MB)  xb bf16    (dead after GEMM)
  // then k_attn overwrites all of d_out with sdp f32; LN runs in-place.
  unsigned short* qkv = (unsigned short*)d_ws;
  unsigned short* w1t = (unsigned short*)d_out;
  unsigned short* xb  = (unsigned short*)((char*)d_out + 6291456);
  float*          sdp = (float*)d_out;

  k_cvt_x<<<MROWS * CC / (256 * 8), 256, 0, stream>>>(x, xb);
  k_tr_w1<<<dim3(CC / 32, N3C / 32), 256, 0, stream>>>(W1, w1t);
  k_qkv_gemm<<<dim3(MROWS / 128, N3C / 128), 256, 0, stream>>>(xb, w1t, b1, qkv);
  k_attn<<<2 * 16 * (TT / 64), 256, 0, stream>>>(qkv, sdp);
  k_ln<<<MROWS, 256, 0, stream>>>(x, gamma, beta, sdp);
}